// Round 8
// baseline (2488.866 us; speedup 1.0000x reference)
//
#include <hip/hip_runtime.h>
#include <hip/hip_fp16.h>
#include <math.h>

// Problem constants (from setup_inputs): B=2, C=256, N=4096
#define NB 2
#define NC 256
#define NN 4096
#define N4 (NN / 4)                    // 1024 float4 per row
#define MAX_ITER 10

#define PBLOCKS 512                    // fused-pass blocks (256 per batch)
#define PROWS 16                       // rows per fused-pass block (4 per wave)

#define LDA 72                         // padded LDS row stride (halfs)

typedef _Float16 half8_t __attribute__((ext_vector_type(8)));
typedef float f32x4 __attribute__((ext_vector_type(4)));
typedef float f32x2 __attribute__((ext_vector_type(2)));

// Decode 16 fp8 (e4m3, packed in uint4) -> 16 floats. HW cvt, gfx950.
__device__ inline void fp8x16_decode(uint4 v, float* o) {
  f32x2 p;
  p = __builtin_amdgcn_cvt_pk_f32_fp8(v.x, false); o[0] = p[0];  o[1] = p[1];
  p = __builtin_amdgcn_cvt_pk_f32_fp8(v.x, true);  o[2] = p[0];  o[3] = p[1];
  p = __builtin_amdgcn_cvt_pk_f32_fp8(v.y, false); o[4] = p[0];  o[5] = p[1];
  p = __builtin_amdgcn_cvt_pk_f32_fp8(v.y, true);  o[6] = p[0];  o[7] = p[1];
  p = __builtin_amdgcn_cvt_pk_f32_fp8(v.z, false); o[8] = p[0];  o[9] = p[1];
  p = __builtin_amdgcn_cvt_pk_f32_fp8(v.z, true);  o[10] = p[0]; o[11] = p[1];
  p = __builtin_amdgcn_cvt_pk_f32_fp8(v.w, false); o[12] = p[0]; o[13] = p[1];
  p = __builtin_amdgcn_cvt_pk_f32_fp8(v.w, true);  o[14] = p[0]; o[15] = p[1];
}

// ---------------------------------------------------------------------------
// 1) inv_norm[b,n] = 1/sqrt(sum_c feats[b,c,n]^2 + 1e-6)
__global__ __launch_bounds__(256) void norms_kernel(
    const float* __restrict__ f1, const float* __restrict__ f2,
    float* __restrict__ inv1, float* __restrict__ inv2) {
  int n = blockIdx.x * 256 + threadIdx.x;
  int b = blockIdx.y;
  const float* f = blockIdx.z ? f2 : f1;
  float* o = blockIdx.z ? inv2 : inv1;
  const float* base = f + (size_t)b * NC * NN + n;
  float s = 0.f;
#pragma unroll 8
  for (int c = 0; c < NC; ++c) {
    float v = base[(size_t)c * NN];
    s = fmaf(v, v, s);
  }
  o[b * NN + n] = 1.0f / sqrtf(s + 1e-6f);
}

// ---------------------------------------------------------------------------
// 1b) prep: f_t[b][n][c] = f[b][c][n] * inv[b][n], cast to f16.
__global__ __launch_bounds__(256) void prep_kernel(
    const float* __restrict__ f1, const float* __restrict__ f2,
    const float* __restrict__ inv1, const float* __restrict__ inv2,
    __half* __restrict__ f1t, __half* __restrict__ f2t) {
  int which = blockIdx.z & 1;
  int b = blockIdx.z >> 1;
  const float* f = which ? f2 : f1;
  const float* inv = which ? inv2 : inv1;
  __half* ft = which ? f2t : f1t;
  int n0 = blockIdx.x * 64;
  int c0 = blockIdx.y * 64;

  __shared__ float T[64][65];
  int t = threadIdx.x;
  int lane = t & 63, grp = t >> 6;
#pragma unroll
  for (int p = 0; p < 16; ++p) {
    int c_in = p * 4 + grp;
    T[lane][c_in] = f[((size_t)b * NC + c0 + c_in) * NN + n0 + lane];
  }
  __syncthreads();
#pragma unroll
  for (int p = 0; p < 16; ++p) {
    int n_out = p * 4 + grp;
    float v = T[n_out][lane] * inv[b * NN + n0 + n_out];
    ft[((size_t)b * NN + n0 + n_out) * NC + c0 + lane] = __float2half(v);
  }
}

// ---------------------------------------------------------------------------
// 2) K[b,i,j] = exp((corr-1)/eps') * (dist < 0.25) via f16 MFMA, fp8 store.
struct __align__(16) SMstage { __half A[128 * LDA]; __half B[128 * LDA]; };
union SMu { SMstage st; unsigned char C8[128 * 128]; };

__global__ __launch_bounds__(256) void kmat_mfma_kernel(
    const __half* __restrict__ f1t, const __half* __restrict__ f2t,
    const float* __restrict__ pc1, const float* __restrict__ pc2,
    const float* __restrict__ g_eps, unsigned char* __restrict__ K) {
  int b = blockIdx.z;
  int i0 = blockIdx.y * 128;
  int j0 = blockIdx.x * 128;

  __shared__ SMu sm;
  __shared__ float p1s[4][128];
  __shared__ float p2s[4][128];

  int tid = threadIdx.x;
  if (tid < 128) {
    int i = i0 + tid;
    float x = pc1[((size_t)b * 3 + 0) * NN + i];
    float y = pc1[((size_t)b * 3 + 1) * NN + i];
    float z = pc1[((size_t)b * 3 + 2) * NN + i];
    p1s[0][tid] = x; p1s[1][tid] = y; p1s[2][tid] = z;
    p1s[3][tid] = x * x + y * y + z * z;
  } else {
    int j = j0 + tid - 128;
    float x = pc2[((size_t)b * 3 + 0) * NN + j];
    float y = pc2[((size_t)b * 3 + 1) * NN + j];
    float z = pc2[((size_t)b * 3 + 2) * NN + j];
    p2s[0][tid - 128] = x; p2s[1][tid - 128] = y; p2s[2][tid - 128] = z;
    p2s[3][tid - 128] = x * x + y * y + z * z;
  }
  float inv_eps = 1.0f / (expf(g_eps[0]) + 0.03f);

  const __half* Ag = f1t + ((size_t)b * NN + i0) * NC;
  const __half* Bg = f2t + ((size_t)b * NN + j0) * NC;

  int lane = tid & 63, wid = tid >> 6;
  int m0 = (wid >> 1) * 64, n0 = (wid & 1) * 64;
  int l15 = lane & 15, quad = lane >> 4;

  f32x4 acc[4][4] = {};

  int sr = tid >> 1, sh = tid & 1;

  for (int kk = 0; kk < NC; kk += 64) {
    __syncthreads();
    {
      const uint4* As = (const uint4*)(Ag + (size_t)sr * NC + kk + sh * 32);
      const uint4* Bs = (const uint4*)(Bg + (size_t)sr * NC + kk + sh * 32);
      uint4* Ad = (uint4*)&sm.st.A[sr * LDA + sh * 32];
      uint4* Bd = (uint4*)&sm.st.B[sr * LDA + sh * 32];
#pragma unroll
      for (int s = 0; s < 4; ++s) Ad[s] = As[s];
#pragma unroll
      for (int s = 0; s < 4; ++s) Bd[s] = Bs[s];
    }
    __syncthreads();
#pragma unroll
    for (int ks = 0; ks < 2; ++ks) {
      half8_t aF[4], bF[4];
#pragma unroll
      for (int mt = 0; mt < 4; ++mt)
        aF[mt] = *(const half8_t*)&sm.st.A[(m0 + mt * 16 + l15) * LDA + ks * 32 + quad * 8];
#pragma unroll
      for (int nt = 0; nt < 4; ++nt)
        bF[nt] = *(const half8_t*)&sm.st.B[(n0 + nt * 16 + l15) * LDA + ks * 32 + quad * 8];
#pragma unroll
      for (int mt = 0; mt < 4; ++mt)
#pragma unroll
        for (int nt = 0; nt < 4; ++nt)
          acc[mt][nt] = __builtin_amdgcn_mfma_f32_16x16x32_f16(
              aF[mt], bF[nt], acc[mt][nt], 0, 0, 0);
    }
  }

  __syncthreads();

  float c2x[4], c2y[4], c2z[4], c2n[4];
#pragma unroll
  for (int nt = 0; nt < 4; ++nt) {
    int c = n0 + nt * 16 + l15;
    c2x[nt] = p2s[0][c]; c2y[nt] = p2s[1][c];
    c2z[nt] = p2s[2][c]; c2n[nt] = p2s[3][c];
  }
#pragma unroll
  for (int mt = 0; mt < 4; ++mt) {
#pragma unroll
    for (int rr = 0; rr < 4; ++rr) {
      int row = m0 + mt * 16 + quad * 4 + rr;
      float px = p1s[0][row], py = p1s[1][row], pz = p1s[2][row];
      float n1 = p1s[3][row];
#pragma unroll
      for (int nt = 0; nt < 4; ++nt) {
        float corr = acc[mt][nt][rr];
        float dist = n1 + c2n[nt] - 2.0f * (px * c2x[nt] + py * c2y[nt] + pz * c2z[nt]);
        float kv = (dist < 0.25f) ? __expf((corr - 1.0f) * inv_eps) : 0.0f;
        unsigned int pk = (unsigned int)__builtin_amdgcn_cvt_pk_fp8_f32(kv, kv, 0, false);
        sm.C8[row * 128 + n0 + nt * 16 + l15] = (unsigned char)(pk & 0xFF);
      }
    }
  }
  __syncthreads();

  // Coalesced fp8 store: 8 threads cover a 128B row, 32 rows per sweep.
  int c8 = tid & 7, rg = tid >> 3;
#pragma unroll
  for (int s = 0; s < 4; ++s) {
    int row = s * 32 + rg;
    uint4 v = *(uint4*)&sm.C8[row * 128 + c8 * 16];
    *(uint4*)&K[((size_t)b * NN + i0 + row) * NN + j0 + c8 * 16] = v;
  }
}

// ---------------------------------------------------------------------------
// 3) Fused Sinkhorn pass over fp8 K, atomic column accumulation.
// Triple-buffered ta: pass t reads ta_read (=t-1 sums), atomically adds into
// ta_acc (=t sums), zeros ta_zero (for pass t+2). b computed inline from
// ta_read. Block g owns 16 rows of batch g>>8 (4 rows/wave). All 4 rows'
// data (16 uint4/lane, 256 B in flight) loaded upfront for MLP; dot uses
// 4 split chains; __powf. LDS block-reduce, then 16 atomicAdd per thread.
__global__ __launch_bounds__(256, 1) void fused_pass_kernel(
    const unsigned char* __restrict__ K, const float* __restrict__ ta_read,
    float* __restrict__ ta_acc, float* __restrict__ ta_zero,
    const float* __restrict__ g_gamma, const float* __restrict__ g_eps,
    int pass) {
  __shared__ float red[4][NN];  // 64 KB

  int g = blockIdx.x;            // 0..511
  int batch = g >> 8;
  int row0 = (g & 255) * PROWS;
  int tid = threadIdx.x;
  int w = tid >> 6, l = tid & 63;
  const unsigned char* Kb = K + (size_t)batch * NN * NN;

  float eps = expf(g_eps[0]) + 0.03f;
  float gam = expf(g_gamma[0]) + 0.03f;
  float power = gam / (gam + eps);
  const float probN = 1.0f / NN;

  // Zero the t+2 buffer (disjoint from ta_read/ta_acc).
  if (g < (NB * NN) / 256) ta_zero[g * 256 + tid] = 0.f;

  // b_t inline from ta_read: lane l covers columns (q*64+l)*16 + 0..15.
  float breg[64];
  if (pass > 0) {
#pragma unroll
    for (int q = 0; q < 4; ++q) {
      const float4* tp = (const float4*)&ta_read[batch * NN + (q * 64 + l) * 16];
#pragma unroll
      for (int s = 0; s < 4; ++s) {
        float4 tv = tp[s];
        breg[q * 16 + s * 4 + 0] = __powf(probN / (tv.x + 1e-8f), power);
        breg[q * 16 + s * 4 + 1] = __powf(probN / (tv.y + 1e-8f), power);
        breg[q * 16 + s * 4 + 2] = __powf(probN / (tv.z + 1e-8f), power);
        breg[q * 16 + s * 4 + 3] = __powf(probN / (tv.w + 1e-8f), power);
      }
    }
  }

  float ps[64];
#pragma unroll
  for (int p = 0; p < 64; ++p) ps[p] = 0.f;

  int rbase = row0 + w * (PROWS / 4);  // 4 rows per wave

  // Load ALL 4 rows upfront: 16 independent 16B loads (256 B/lane in flight).
  uint4 kraw[4][4];
#pragma unroll
  for (int r = 0; r < 4; ++r) {
    const uint4* Kr = (const uint4*)(Kb + (size_t)(rbase + r) * NN);
#pragma unroll
    for (int q = 0; q < 4; ++q) kraw[r][q] = Kr[q * 64 + l];
  }

#pragma unroll
  for (int r = 0; r < 4; ++r) {
    float wgt;
    if (pass == 0) {
      wgt = probN;  // a_0 = 1/N
    } else {
      float a0 = 0.f, a1 = 0.f, a2 = 0.f, a3 = 0.f;  // 4 split chains
#pragma unroll
      for (int q = 0; q < 4; ++q) {
        float kf[16];
        fp8x16_decode(kraw[r][q], kf);
#pragma unroll
        for (int s = 0; s < 4; ++s) {
          a0 = fmaf(kf[s * 4 + 0], breg[q * 16 + s * 4 + 0], a0);
          a1 = fmaf(kf[s * 4 + 1], breg[q * 16 + s * 4 + 1], a1);
          a2 = fmaf(kf[s * 4 + 2], breg[q * 16 + s * 4 + 2], a2);
          a3 = fmaf(kf[s * 4 + 3], breg[q * 16 + s * 4 + 3], a3);
        }
      }
      float kbs = (a0 + a1) + (a2 + a3);
#pragma unroll
      for (int off = 1; off < 64; off <<= 1) kbs += __shfl_xor(kbs, off, 64);
      wgt = __powf(probN / (kbs + 1e-8f), power);  // a_t[row]
    }
#pragma unroll
    for (int q = 0; q < 4; ++q) {
      float kf[16];
      fp8x16_decode(kraw[r][q], kf);
#pragma unroll
      for (int e = 0; e < 16; ++e)
        ps[q * 16 + e] = fmaf(kf[e], wgt, ps[q * 16 + e]);
    }
  }

  // block-reduce 4 waves' ps -> atomicAdd into ta_acc
#pragma unroll
  for (int q = 0; q < 4; ++q) {
#pragma unroll
    for (int s = 0; s < 4; ++s) {
      *(float4*)&red[w][(q * 64 + l) * 16 + s * 4] =
          make_float4(ps[q * 16 + s * 4 + 0], ps[q * 16 + s * 4 + 1],
                      ps[q * 16 + s * 4 + 2], ps[q * 16 + s * 4 + 3]);
    }
  }
  __syncthreads();
  float* ta = ta_acc + batch * NN;
#pragma unroll
  for (int v4 = 0; v4 < 4; ++v4) {
    int c = tid * 16 + v4 * 4;
    float4 s0 = *(float4*)&red[0][c];
    float4 s1 = *(float4*)&red[1][c];
    float4 s2 = *(float4*)&red[2][c];
    float4 s3 = *(float4*)&red[3][c];
    atomicAdd(&ta[c + 0], (s0.x + s1.x) + (s2.x + s3.x));
    atomicAdd(&ta[c + 1], (s0.y + s1.y) + (s2.y + s3.y));
    atomicAdd(&ta[c + 2], (s0.z + s1.z) + (s2.z + s3.z));
    atomicAdd(&ta[c + 3], (s0.w + s1.w) + (s2.w + s3.w));
  }
}

// ---------------------------------------------------------------------------
// 3b) bvec = (probN / (ta + 1e-8))^power — final b for the flow pass.
__global__ __launch_bounds__(256) void bfinal_kernel(
    const float* __restrict__ ta, float* __restrict__ bvec,
    const float* __restrict__ g_gamma, const float* __restrict__ g_eps) {
  int i = blockIdx.x * 256 + threadIdx.x;
  float eps = expf(g_eps[0]) + 0.03f;
  float gam = expf(g_gamma[0]) + 0.03f;
  float power = gam / (gam + eps);
  bvec[i] = __powf((1.0f / NN) / (ta[i] + 1e-8f), power);
}

// ---------------------------------------------------------------------------
// 4) Final pass fused: Kb + Sxyz, then a_10 and flow. fp8 K.
__global__ __launch_bounds__(256) void kb_flow_kernel(
    const unsigned char* __restrict__ K, const float* __restrict__ bvec,
    const float* __restrict__ pc1, const float* __restrict__ pc2,
    const float* __restrict__ g_gamma, const float* __restrict__ g_eps,
    float* __restrict__ out) {
  int b = blockIdx.y;
  int i = blockIdx.x;
  int j16 = threadIdx.x;  // 0..255
  const uint4* K16 = (const uint4*)(K + ((size_t)b * NN + i) * NN);
  uint4 kv = K16[j16];
  float kf[16];
  fp8x16_decode(kv, kf);

  const float4* b4 = (const float4*)&bvec[b * NN + j16 * 16];
  const float* p2 = pc2 + (size_t)b * 3 * NN;
  const float4* p2x = (const float4*)&p2[0 * NN + j16 * 16];
  const float4* p2y = (const float4*)&p2[1 * NN + j16 * 16];
  const float4* p2z = (const float4*)&p2[2 * NN + j16 * 16];

  float S = 0.f, Sx = 0.f, Sy = 0.f, Sz = 0.f;
#pragma unroll
  for (int s = 0; s < 4; ++s) {
    float4 bb = b4[s];
    float4 xx = p2x[s], yy = p2y[s], zz = p2z[s];
    float w0 = kf[s * 4 + 0] * bb.x;
    float w1 = kf[s * 4 + 1] * bb.y;
    float w2 = kf[s * 4 + 2] * bb.z;
    float w3 = kf[s * 4 + 3] * bb.w;
    S += (w0 + w1) + (w2 + w3);
    Sx += w0 * xx.x + w1 * xx.y + w2 * xx.z + w3 * xx.w;
    Sy += w0 * yy.x + w1 * yy.y + w2 * yy.z + w3 * yy.w;
    Sz += w0 * zz.x + w1 * zz.y + w2 * zz.z + w3 * zz.w;
  }
#pragma unroll
  for (int off = 32; off; off >>= 1) {
    S  += __shfl_down(S, off, 64);
    Sx += __shfl_down(Sx, off, 64);
    Sy += __shfl_down(Sy, off, 64);
    Sz += __shfl_down(Sz, off, 64);
  }
  __shared__ float red[4][4];
  int lane = threadIdx.x & 63, wid = threadIdx.x >> 6;
  if (lane == 0) {
    red[wid][0] = S; red[wid][1] = Sx; red[wid][2] = Sy; red[wid][3] = Sz;
  }
  __syncthreads();
  if (threadIdx.x == 0) {
    float kb  = red[0][0] + red[1][0] + red[2][0] + red[3][0];
    float Sxt = red[0][1] + red[1][1] + red[2][1] + red[3][1];
    float Syt = red[0][2] + red[1][2] + red[2][2] + red[3][2];
    float Szt = red[0][3] + red[1][3] + red[2][3] + red[3][3];
    float eps = expf(g_eps[0]) + 0.03f;
    float gam = expf(g_gamma[0]) + 0.03f;
    float power = gam / (gam + eps);
    float av = powf((1.0f / NN) / (kb + 1e-8f), power);
    float denom = av * kb + 1e-6f;
    const float* p1 = pc1 + (size_t)b * 3 * NN;
    size_t o = ((size_t)b * NN + i) * 3;
    out[o + 0] = av * Sxt / denom - p1[0 * NN + i];
    out[o + 1] = av * Syt / denom - p1[1 * NN + i];
    out[o + 2] = av * Szt / denom - p1[2 * NN + i];
  }
}

// ---------------------------------------------------------------------------
extern "C" void kernel_launch(void* const* d_in, const int* in_sizes, int n_in,
                              void* d_out, int out_size, void* d_ws,
                              size_t ws_size, hipStream_t stream) {
  const float* pc1 = (const float*)d_in[0];
  const float* pc2 = (const float*)d_in[1];
  const float* f1 = (const float*)d_in[2];
  const float* f2 = (const float*)d_in[3];
  const float* g_gamma = (const float*)d_in[4];
  const float* g_eps = (const float*)d_in[5];
  float* out = (float*)d_out;

  // Workspace layout
  size_t off = 0;
  char* ws = (char*)d_ws;
  unsigned char* K = (unsigned char*)(ws + off);
  off += (size_t)NB * NN * NN * sizeof(unsigned char);                             // 33.5 MB
  __half* f1t = (__half*)(ws + off); off += (size_t)NB * NN * NC * sizeof(__half); // 4 MB
  __half* f2t = (__half*)(ws + off); off += (size_t)NB * NN * NC * sizeof(__half); // 4 MB
  float* inv1 = (float*)(ws + off); off += (size_t)NB * NN * sizeof(float);
  float* inv2 = (float*)(ws + off); off += (size_t)NB * NN * sizeof(float);
  float* bvec = (float*)(ws + off); off += (size_t)NB * NN * sizeof(float);
  float* ta[3];
  for (int t = 0; t < 3; ++t) {
    ta[t] = (float*)(ws + off); off += (size_t)NB * NN * sizeof(float);            // 32 KB each
  }
  if (ws_size < off) return;  // workspace too small

  norms_kernel<<<dim3(NN / 256, NB, 2), 256, 0, stream>>>(f1, f2, inv1, inv2);
  prep_kernel<<<dim3(NN / 64, NC / 64, NB * 2), 256, 0, stream>>>(
      f1, f2, inv1, inv2, f1t, f2t);
  kmat_mfma_kernel<<<dim3(NN / 128, NN / 128, NB), 256, 0, stream>>>(
      f1t, f2t, pc1, pc2, g_eps, K);

  // ta[0] must start zeroed (receives pass 0's atomics).
  hipMemsetAsync(ta[0], 0, (size_t)NB * NN * sizeof(float), stream);

  for (int it = 0; it < MAX_ITER; ++it) {
    // pass it: read ta[(it+2)%3] (it-1 sums), accumulate ta[it%3],
    // zero ta[(it+1)%3] (for pass it+2).
    fused_pass_kernel<<<dim3(PBLOCKS), 256, 0, stream>>>(
        K, ta[(it + 2) % 3], ta[it % 3], ta[(it + 1) % 3],
        g_gamma, g_eps, it);
  }

  bfinal_kernel<<<dim3((NB * NN) / 256), 256, 0, stream>>>(
      ta[(MAX_ITER - 1) % 3], bvec, g_gamma, g_eps);
  kb_flow_kernel<<<dim3(NN, NB), 256, 0, stream>>>(K, bvec, pc1, pc2,
                                                   g_gamma, g_eps, out);
}

// Round 9
// 397.554 us; speedup vs baseline: 6.2605x; 6.2605x over previous
//
#include <hip/hip_runtime.h>
#include <hip/hip_fp16.h>
#include <math.h>

// Problem constants (from setup_inputs): B=2, C=256, N=4096
#define NB 2
#define NC 256
#define NN 4096
#define N4 (NN / 4)                    // 1024 float4 per row
#define MAX_ITER 10

#define PBLOCKS 512                    // fused-pass blocks (256 per batch)
#define PCHUNKS 256                    // partial chunks per batch
#define PROWS 16                       // rows per fused-pass block (4 per wave)

#define LDA 72                         // padded LDS row stride (halfs)

typedef _Float16 half8_t __attribute__((ext_vector_type(8)));
typedef float f32x4 __attribute__((ext_vector_type(4)));
typedef float f32x2 __attribute__((ext_vector_type(2)));

// Decode 16 fp8 (e4m3, packed in uint4) -> 16 floats. HW cvt, gfx950.
__device__ inline void fp8x16_decode(uint4 v, float* o) {
  f32x2 p;
  p = __builtin_amdgcn_cvt_pk_f32_fp8(v.x, false); o[0] = p[0];  o[1] = p[1];
  p = __builtin_amdgcn_cvt_pk_f32_fp8(v.x, true);  o[2] = p[0];  o[3] = p[1];
  p = __builtin_amdgcn_cvt_pk_f32_fp8(v.y, false); o[4] = p[0];  o[5] = p[1];
  p = __builtin_amdgcn_cvt_pk_f32_fp8(v.y, true);  o[6] = p[0];  o[7] = p[1];
  p = __builtin_amdgcn_cvt_pk_f32_fp8(v.z, false); o[8] = p[0];  o[9] = p[1];
  p = __builtin_amdgcn_cvt_pk_f32_fp8(v.z, true);  o[10] = p[0]; o[11] = p[1];
  p = __builtin_amdgcn_cvt_pk_f32_fp8(v.w, false); o[12] = p[0]; o[13] = p[1];
  p = __builtin_amdgcn_cvt_pk_f32_fp8(v.w, true);  o[14] = p[0]; o[15] = p[1];
}

// ---------------------------------------------------------------------------
// 1) inv_norm[b,n] = 1/sqrt(sum_c feats[b,c,n]^2 + 1e-6)
__global__ __launch_bounds__(256) void norms_kernel(
    const float* __restrict__ f1, const float* __restrict__ f2,
    float* __restrict__ inv1, float* __restrict__ inv2) {
  int n = blockIdx.x * 256 + threadIdx.x;
  int b = blockIdx.y;
  const float* f = blockIdx.z ? f2 : f1;
  float* o = blockIdx.z ? inv2 : inv1;
  const float* base = f + (size_t)b * NC * NN + n;
  float s = 0.f;
#pragma unroll 8
  for (int c = 0; c < NC; ++c) {
    float v = base[(size_t)c * NN];
    s = fmaf(v, v, s);
  }
  o[b * NN + n] = 1.0f / sqrtf(s + 1e-6f);
}

// ---------------------------------------------------------------------------
// 1b) prep: f_t[b][n][c] = f[b][c][n] * inv[b][n], cast to f16.
__global__ __launch_bounds__(256) void prep_kernel(
    const float* __restrict__ f1, const float* __restrict__ f2,
    const float* __restrict__ inv1, const float* __restrict__ inv2,
    __half* __restrict__ f1t, __half* __restrict__ f2t) {
  int which = blockIdx.z & 1;
  int b = blockIdx.z >> 1;
  const float* f = which ? f2 : f1;
  const float* inv = which ? inv2 : inv1;
  __half* ft = which ? f2t : f1t;
  int n0 = blockIdx.x * 64;
  int c0 = blockIdx.y * 64;

  __shared__ float T[64][65];
  int t = threadIdx.x;
  int lane = t & 63, grp = t >> 6;
#pragma unroll
  for (int p = 0; p < 16; ++p) {
    int c_in = p * 4 + grp;
    T[lane][c_in] = f[((size_t)b * NC + c0 + c_in) * NN + n0 + lane];
  }
  __syncthreads();
#pragma unroll
  for (int p = 0; p < 16; ++p) {
    int n_out = p * 4 + grp;
    float v = T[n_out][lane] * inv[b * NN + n0 + n_out];
    ft[((size_t)b * NN + n0 + n_out) * NC + c0 + lane] = __float2half(v);
  }
}

// ---------------------------------------------------------------------------
// 2) K[b,i,j] = exp((corr-1)/eps') * (dist < 0.25) via f16 MFMA, fp8 store.
struct __align__(16) SMstage { __half A[128 * LDA]; __half B[128 * LDA]; };
union SMu { SMstage st; unsigned char C8[128 * 128]; };

__global__ __launch_bounds__(256) void kmat_mfma_kernel(
    const __half* __restrict__ f1t, const __half* __restrict__ f2t,
    const float* __restrict__ pc1, const float* __restrict__ pc2,
    const float* __restrict__ g_eps, unsigned char* __restrict__ K) {
  int b = blockIdx.z;
  int i0 = blockIdx.y * 128;
  int j0 = blockIdx.x * 128;

  __shared__ SMu sm;
  __shared__ float p1s[4][128];
  __shared__ float p2s[4][128];

  int tid = threadIdx.x;
  if (tid < 128) {
    int i = i0 + tid;
    float x = pc1[((size_t)b * 3 + 0) * NN + i];
    float y = pc1[((size_t)b * 3 + 1) * NN + i];
    float z = pc1[((size_t)b * 3 + 2) * NN + i];
    p1s[0][tid] = x; p1s[1][tid] = y; p1s[2][tid] = z;
    p1s[3][tid] = x * x + y * y + z * z;
  } else {
    int j = j0 + tid - 128;
    float x = pc2[((size_t)b * 3 + 0) * NN + j];
    float y = pc2[((size_t)b * 3 + 1) * NN + j];
    float z = pc2[((size_t)b * 3 + 2) * NN + j];
    p2s[0][tid - 128] = x; p2s[1][tid - 128] = y; p2s[2][tid - 128] = z;
    p2s[3][tid - 128] = x * x + y * y + z * z;
  }
  float inv_eps = 1.0f / (expf(g_eps[0]) + 0.03f);

  const __half* Ag = f1t + ((size_t)b * NN + i0) * NC;
  const __half* Bg = f2t + ((size_t)b * NN + j0) * NC;

  int lane = tid & 63, wid = tid >> 6;
  int m0 = (wid >> 1) * 64, n0 = (wid & 1) * 64;
  int l15 = lane & 15, quad = lane >> 4;

  f32x4 acc[4][4] = {};

  int sr = tid >> 1, sh = tid & 1;

  for (int kk = 0; kk < NC; kk += 64) {
    __syncthreads();
    {
      const uint4* As = (const uint4*)(Ag + (size_t)sr * NC + kk + sh * 32);
      const uint4* Bs = (const uint4*)(Bg + (size_t)sr * NC + kk + sh * 32);
      uint4* Ad = (uint4*)&sm.st.A[sr * LDA + sh * 32];
      uint4* Bd = (uint4*)&sm.st.B[sr * LDA + sh * 32];
#pragma unroll
      for (int s = 0; s < 4; ++s) Ad[s] = As[s];
#pragma unroll
      for (int s = 0; s < 4; ++s) Bd[s] = Bs[s];
    }
    __syncthreads();
#pragma unroll
    for (int ks = 0; ks < 2; ++ks) {
      half8_t aF[4], bF[4];
#pragma unroll
      for (int mt = 0; mt < 4; ++mt)
        aF[mt] = *(const half8_t*)&sm.st.A[(m0 + mt * 16 + l15) * LDA + ks * 32 + quad * 8];
#pragma unroll
      for (int nt = 0; nt < 4; ++nt)
        bF[nt] = *(const half8_t*)&sm.st.B[(n0 + nt * 16 + l15) * LDA + ks * 32 + quad * 8];
#pragma unroll
      for (int mt = 0; mt < 4; ++mt)
#pragma unroll
        for (int nt = 0; nt < 4; ++nt)
          acc[mt][nt] = __builtin_amdgcn_mfma_f32_16x16x32_f16(
              aF[mt], bF[nt], acc[mt][nt], 0, 0, 0);
    }
  }

  __syncthreads();

  float c2x[4], c2y[4], c2z[4], c2n[4];
#pragma unroll
  for (int nt = 0; nt < 4; ++nt) {
    int c = n0 + nt * 16 + l15;
    c2x[nt] = p2s[0][c]; c2y[nt] = p2s[1][c];
    c2z[nt] = p2s[2][c]; c2n[nt] = p2s[3][c];
  }
#pragma unroll
  for (int mt = 0; mt < 4; ++mt) {
#pragma unroll
    for (int rr = 0; rr < 4; ++rr) {
      int row = m0 + mt * 16 + quad * 4 + rr;
      float px = p1s[0][row], py = p1s[1][row], pz = p1s[2][row];
      float n1 = p1s[3][row];
#pragma unroll
      for (int nt = 0; nt < 4; ++nt) {
        float corr = acc[mt][nt][rr];
        float dist = n1 + c2n[nt] - 2.0f * (px * c2x[nt] + py * c2y[nt] + pz * c2z[nt]);
        float kv = (dist < 0.25f) ? __expf((corr - 1.0f) * inv_eps) : 0.0f;
        unsigned int pk = (unsigned int)__builtin_amdgcn_cvt_pk_fp8_f32(kv, kv, 0, false);
        sm.C8[row * 128 + n0 + nt * 16 + l15] = (unsigned char)(pk & 0xFF);
      }
    }
  }
  __syncthreads();

  // Coalesced fp8 store: 8 threads cover a 128B row, 32 rows per sweep.
  int c8 = tid & 7, rg = tid >> 3;
#pragma unroll
  for (int s = 0; s < 4; ++s) {
    int row = s * 32 + rg;
    uint4 v = *(uint4*)&sm.C8[row * 128 + c8 * 16];
    *(uint4*)&K[((size_t)b * NN + i0 + row) * NN + j0 + c8 * 16] = v;
  }
}

// ---------------------------------------------------------------------------
// 3) Fused Sinkhorn pass over fp8 K: ONE K read serves both matvecs.
// Block g (of 512) owns PROWS=16 rows of batch g>>8 (4 rows/wave).
// ALL 4 rows loaded upfront (16 independent uint4 loads, 256 B/lane in
// flight — R7 had only 64 B and was latency-bound). Per row: kb = K[r,:]·b_t
// (4 split FMA chains, wave reduce) -> a = __powf(...) -> ps += a*row.
// Block-reduce via LDS -> part[g][:] (NO global atomics: R8's 2M atomicAdds
// to 8K addrs caused 64 MB of memory-side RMW traffic and 244 µs/pass).
// Regs: breg 64 + ps 64 + kraw 64 + temps ~= 220 < 256 -> 2 waves/EU,
// matching the 64 KB LDS limit (2 blocks/CU). (256,1) avoids the R5 spill.
__global__ __launch_bounds__(256, 1) void fused_pass_kernel(
    const unsigned char* __restrict__ K, const float* __restrict__ bvec,
    float* __restrict__ part, const float* __restrict__ g_gamma,
    const float* __restrict__ g_eps, int pass) {
  __shared__ float red[4][NN];  // 64 KB

  int g = blockIdx.x;            // 0..511
  int batch = g >> 8;
  int row0 = (g & 255) * PROWS;
  int tid = threadIdx.x;
  int w = tid >> 6, l = tid & 63;
  const unsigned char* Kb = K + (size_t)batch * NN * NN;

  float eps = expf(g_eps[0]) + 0.03f;
  float gam = expf(g_gamma[0]) + 0.03f;
  float power = gam / (gam + eps);
  const float probN = 1.0f / NN;

  // b_t into registers: lane l covers columns (q*64+l)*16 + 0..15, q=0..3.
  float breg[64];
  if (pass > 0) {
#pragma unroll
    for (int q = 0; q < 4; ++q) {
      const float4* bp = (const float4*)&bvec[batch * NN + (q * 64 + l) * 16];
#pragma unroll
      for (int s = 0; s < 4; ++s) {
        float4 bb = bp[s];
        breg[q * 16 + s * 4 + 0] = bb.x;
        breg[q * 16 + s * 4 + 1] = bb.y;
        breg[q * 16 + s * 4 + 2] = bb.z;
        breg[q * 16 + s * 4 + 3] = bb.w;
      }
    }
  }

  float ps[64];
#pragma unroll
  for (int p = 0; p < 64; ++p) ps[p] = 0.f;

  int rbase = row0 + w * (PROWS / 4);  // 4 rows per wave

  // Load ALL 4 rows upfront: 16 independent 16B loads (256 B/lane in flight).
  uint4 kraw[4][4];
#pragma unroll
  for (int r = 0; r < 4; ++r) {
    const uint4* Kr = (const uint4*)(Kb + (size_t)(rbase + r) * NN);
#pragma unroll
    for (int q = 0; q < 4; ++q) kraw[r][q] = Kr[q * 64 + l];
  }

#pragma unroll
  for (int r = 0; r < 4; ++r) {
    float wgt;
    if (pass == 0) {
      wgt = probN;  // a_0 = 1/N
    } else {
      float a0 = 0.f, a1 = 0.f, a2 = 0.f, a3 = 0.f;  // 4 split chains
#pragma unroll
      for (int q = 0; q < 4; ++q) {
        float kf[16];
        fp8x16_decode(kraw[r][q], kf);
#pragma unroll
        for (int s = 0; s < 4; ++s) {
          a0 = fmaf(kf[s * 4 + 0], breg[q * 16 + s * 4 + 0], a0);
          a1 = fmaf(kf[s * 4 + 1], breg[q * 16 + s * 4 + 1], a1);
          a2 = fmaf(kf[s * 4 + 2], breg[q * 16 + s * 4 + 2], a2);
          a3 = fmaf(kf[s * 4 + 3], breg[q * 16 + s * 4 + 3], a3);
        }
      }
      float kbs = (a0 + a1) + (a2 + a3);
#pragma unroll
      for (int off = 1; off < 64; off <<= 1) kbs += __shfl_xor(kbs, off, 64);
      wgt = __powf(probN / (kbs + 1e-8f), power);  // a_t[row]
    }
#pragma unroll
    for (int q = 0; q < 4; ++q) {
      float kf[16];
      fp8x16_decode(kraw[r][q], kf);
#pragma unroll
      for (int e = 0; e < 16; ++e)
        ps[q * 16 + e] = fmaf(kf[e], wgt, ps[q * 16 + e]);
    }
  }

  // block-reduce 4 waves' ps -> part[g][:] (coalesced float4 stores)
#pragma unroll
  for (int q = 0; q < 4; ++q) {
#pragma unroll
    for (int s = 0; s < 4; ++s) {
      *(float4*)&red[w][(q * 64 + l) * 16 + s * 4] =
          make_float4(ps[q * 16 + s * 4 + 0], ps[q * 16 + s * 4 + 1],
                      ps[q * 16 + s * 4 + 2], ps[q * 16 + s * 4 + 3]);
    }
  }
  __syncthreads();
#pragma unroll
  for (int v4 = 0; v4 < 4; ++v4) {
    int c = v4 * 1024 + tid * 4;  // lanes 16B apart -> coalesced
    float4 s0 = *(float4*)&red[0][c];
    float4 s1 = *(float4*)&red[1][c];
    float4 s2 = *(float4*)&red[2][c];
    float4 s3 = *(float4*)&red[3][c];
    float4 o;
    o.x = (s0.x + s1.x) + (s2.x + s3.x);
    o.y = (s0.y + s1.y) + (s2.y + s3.y);
    o.z = (s0.z + s1.z) + (s2.z + s3.z);
    o.w = (s0.w + s1.w) + (s2.w + s3.w);
    *(float4*)&part[(size_t)g * NN + c] = o;
  }
}

// ---------------------------------------------------------------------------
// 3b) b[j] = (probN / (sum_k part[b,k,j] + 1e-8))^power
// 64 cols x 4 k-slices per block; grid (NN/64, NB) = 128 blocks.
__global__ __launch_bounds__(256) void breduce_kernel(
    const float* __restrict__ part, float* __restrict__ bvec,
    const float* __restrict__ g_gamma, const float* __restrict__ g_eps) {
  int b = blockIdx.y;
  int c0 = blockIdx.x * 64;
  int t = threadIdx.x;
  int cl = t & 63, kg = t >> 6;
  const float* p = part + (size_t)(b * PCHUNKS + kg * 64) * NN + c0 + cl;
  float s = 0.f;
#pragma unroll 8
  for (int k = 0; k < 64; ++k) s += p[(size_t)k * NN];
  __shared__ float red[4][64];
  red[kg][cl] = s;
  __syncthreads();
  if (t < 64) {
    float tot = (red[0][t] + red[1][t]) + (red[2][t] + red[3][t]);
    float eps = expf(g_eps[0]) + 0.03f;
    float gam = expf(g_gamma[0]) + 0.03f;
    float power = gam / (gam + eps);
    bvec[b * NN + c0 + t] = __powf((1.0f / NN) / (tot + 1e-8f), power);
  }
}

// ---------------------------------------------------------------------------
// 4) Final pass fused: Kb + Sxyz, then a_10 and flow. fp8 K.
__global__ __launch_bounds__(256) void kb_flow_kernel(
    const unsigned char* __restrict__ K, const float* __restrict__ bvec,
    const float* __restrict__ pc1, const float* __restrict__ pc2,
    const float* __restrict__ g_gamma, const float* __restrict__ g_eps,
    float* __restrict__ out) {
  int b = blockIdx.y;
  int i = blockIdx.x;
  int j16 = threadIdx.x;  // 0..255
  const uint4* K16 = (const uint4*)(K + ((size_t)b * NN + i) * NN);
  uint4 kv = K16[j16];
  float kf[16];
  fp8x16_decode(kv, kf);

  const float4* b4 = (const float4*)&bvec[b * NN + j16 * 16];
  const float* p2 = pc2 + (size_t)b * 3 * NN;
  const float4* p2x = (const float4*)&p2[0 * NN + j16 * 16];
  const float4* p2y = (const float4*)&p2[1 * NN + j16 * 16];
  const float4* p2z = (const float4*)&p2[2 * NN + j16 * 16];

  float S = 0.f, Sx = 0.f, Sy = 0.f, Sz = 0.f;
#pragma unroll
  for (int s = 0; s < 4; ++s) {
    float4 bb = b4[s];
    float4 xx = p2x[s], yy = p2y[s], zz = p2z[s];
    float w0 = kf[s * 4 + 0] * bb.x;
    float w1 = kf[s * 4 + 1] * bb.y;
    float w2 = kf[s * 4 + 2] * bb.z;
    float w3 = kf[s * 4 + 3] * bb.w;
    S += (w0 + w1) + (w2 + w3);
    Sx += w0 * xx.x + w1 * xx.y + w2 * xx.z + w3 * xx.w;
    Sy += w0 * yy.x + w1 * yy.y + w2 * yy.z + w3 * yy.w;
    Sz += w0 * zz.x + w1 * zz.y + w2 * zz.z + w3 * zz.w;
  }
#pragma unroll
  for (int off = 32; off; off >>= 1) {
    S  += __shfl_down(S, off, 64);
    Sx += __shfl_down(Sx, off, 64);
    Sy += __shfl_down(Sy, off, 64);
    Sz += __shfl_down(Sz, off, 64);
  }
  __shared__ float red[4][4];
  int lane = threadIdx.x & 63, wid = threadIdx.x >> 6;
  if (lane == 0) {
    red[wid][0] = S; red[wid][1] = Sx; red[wid][2] = Sy; red[wid][3] = Sz;
  }
  __syncthreads();
  if (threadIdx.x == 0) {
    float kb  = red[0][0] + red[1][0] + red[2][0] + red[3][0];
    float Sxt = red[0][1] + red[1][1] + red[2][1] + red[3][1];
    float Syt = red[0][2] + red[1][2] + red[2][2] + red[3][2];
    float Szt = red[0][3] + red[1][3] + red[2][3] + red[3][3];
    float eps = expf(g_eps[0]) + 0.03f;
    float gam = expf(g_gamma[0]) + 0.03f;
    float power = gam / (gam + eps);
    float av = powf((1.0f / NN) / (kb + 1e-8f), power);
    float denom = av * kb + 1e-6f;
    const float* p1 = pc1 + (size_t)b * 3 * NN;
    size_t o = ((size_t)b * NN + i) * 3;
    out[o + 0] = av * Sxt / denom - p1[0 * NN + i];
    out[o + 1] = av * Syt / denom - p1[1 * NN + i];
    out[o + 2] = av * Szt / denom - p1[2 * NN + i];
  }
}

// ---------------------------------------------------------------------------
extern "C" void kernel_launch(void* const* d_in, const int* in_sizes, int n_in,
                              void* d_out, int out_size, void* d_ws,
                              size_t ws_size, hipStream_t stream) {
  const float* pc1 = (const float*)d_in[0];
  const float* pc2 = (const float*)d_in[1];
  const float* f1 = (const float*)d_in[2];
  const float* f2 = (const float*)d_in[3];
  const float* g_gamma = (const float*)d_in[4];
  const float* g_eps = (const float*)d_in[5];
  float* out = (float*)d_out;

  // Workspace layout
  size_t off = 0;
  char* ws = (char*)d_ws;
  unsigned char* K = (unsigned char*)(ws + off);
  off += (size_t)NB * NN * NN * sizeof(unsigned char);                             // 33.5 MB
  __half* f1t = (__half*)(ws + off); off += (size_t)NB * NN * NC * sizeof(__half); // 4 MB
  __half* f2t = (__half*)(ws + off); off += (size_t)NB * NN * NC * sizeof(__half); // 4 MB
  float* inv1 = (float*)(ws + off); off += (size_t)NB * NN * sizeof(float);
  float* inv2 = (float*)(ws + off); off += (size_t)NB * NN * sizeof(float);
  float* bvec = (float*)(ws + off); off += (size_t)NB * NN * sizeof(float);
  float* part = (float*)(ws + off); off += (size_t)PBLOCKS * NN * sizeof(float);   // 8 MB
  if (ws_size < off) return;  // workspace too small

  norms_kernel<<<dim3(NN / 256, NB, 2), 256, 0, stream>>>(f1, f2, inv1, inv2);
  prep_kernel<<<dim3(NN / 64, NC / 64, NB * 2), 256, 0, stream>>>(
      f1, f2, inv1, inv2, f1t, f2t);
  kmat_mfma_kernel<<<dim3(NN / 128, NN / 128, NB), 256, 0, stream>>>(
      f1t, f2t, pc1, pc2, g_eps, K);

  for (int it = 0; it < MAX_ITER; ++it) {
    fused_pass_kernel<<<dim3(PBLOCKS), 256, 0, stream>>>(
        K, bvec, part, g_gamma, g_eps, it);
    breduce_kernel<<<dim3(NN / 64, NB), 256, 0, stream>>>(
        part, bvec, g_gamma, g_eps);
  }

  kb_flow_kernel<<<dim3(NN, NB), 256, 0, stream>>>(K, bvec, pc1, pc2,
                                                   g_gamma, g_eps, out);
}